// Round 5
// baseline (6594.722 us; speedup 1.0000x reference)
//
#include <hip/hip_runtime.h>
#include <hip/hip_bf16.h>
#include <cfloat>

// K-means, 16 independent spaces. x: (32768, 16, 64) fp32. Output: (16, 256, 64) fp32.
#define NS 16
#define NPTS 32768
#define DIM 64
#define NC 256
#define NITER 5
#define HALF 128                                 // centroids per thread-half

constexpr int TPB = 512;
constexpr int CHUNKS = 16;                       // 256 blocks = 1/CU
constexpr int PTS_PER_BLOCK = NPTS / CHUNKS;     // 2048
constexpr int TILE = 256;                        // points staged in LDS at once
constexpr int NTILES = PTS_PER_BLOCK / TILE;     // 8

// c0[s][k][d] = x[k][s][d]; also c2[s][k] = sum_d c^2
__global__ __launch_bounds__(256) void kminit(const float* __restrict__ x,
                                              float* __restrict__ c,
                                              float* __restrict__ c2) {
  const int tid = threadIdx.x;
  const int g = blockIdx.x * 4 + (tid >> 6);
  const int lane = tid & 63;
  const int s = g >> 8;
  const int k = g & 255;
  float v = x[(size_t)k * (NS * DIM) + s * DIM + lane];
  c[(size_t)g * DIM + lane] = v;
  float sq = v * v;
  #pragma unroll
  for (int off = 32; off; off >>= 1) sq += __shfl_xor(sq, off);
  if (lane == 0) c2[g] = sq;
}

// c = counts>0 ? sums/max(counts,1) : c ; refresh c2
__global__ __launch_bounds__(256) void kmupdate(float* __restrict__ c,
                                                const float* __restrict__ sums,
                                                const float* __restrict__ counts,
                                                float* __restrict__ c2) {
  const int tid = threadIdx.x;
  const int g = blockIdx.x * 4 + (tid >> 6);
  const int lane = tid & 63;
  const float cnt = counts[g];
  const size_t idx = (size_t)g * DIM + lane;
  const float cold = c[idx];
  const float v = (cnt > 0.f) ? (sums[idx] / fmaxf(cnt, 1.f)) : cold;
  c[idx] = v;
  float sq = v * v;
  #pragma unroll
  for (int off = 32; off; off >>= 1) sq += __shfl_xor(sq, off);
  if (lane == 0) c2[g] = sq;
}

// Fused assign + accumulate, restructured (R4 post-mortem):
//  - x tile lives in LDS transposed xt[d][p]; inner loop = ds_read_b32
//    (lanes -> consecutive p, conflict-free) + SGPR-sourced FMAs.
//  - per-thread state ~40 VGPRs (8 float4 staging + 4 accum) -> nothing to spill
//    (R1/R4 both spilled the xv[64] per-thread array: 256 B/point scratch
//    traffic = 114 MB/dispatch, visible in WRITE_SIZE).
//  - 512 threads = 256 points x 2 centroid-halves; halves merged via LDS;
//    strict < with h0 (lower k) priority == jnp.argmin first-min tie-break.
__global__ __launch_bounds__(TPB)
__attribute__((amdgpu_waves_per_eu(2, 2)))
void kmassign(const float* __restrict__ x,
              const float* __restrict__ c,
              const float* __restrict__ c2,
              float* __restrict__ sums,
              float* __restrict__ counts) {
  __shared__ float xt[DIM][TILE];   // 64 KiB transposed point tile
  __shared__ float ss[DIM * NC];    // 64 KiB partial sums [d][k]
  __shared__ float sd[TILE];        // h1 best dist
  __shared__ int   si[TILE];        // h1 best idx
  __shared__ float scnt[NC];        // per-block counts

  const int tid = threadIdx.x;
  const int s = blockIdx.x & (NS - 1);
  const int chunk = blockIdx.x >> 4;

  for (int i = tid; i < DIM * NC; i += TPB) ss[i] = 0.f;
  if (tid < NC) scnt[tid] = 0.f;

  const float* __restrict__ cb = c + (size_t)s * NC * DIM;   // block-uniform -> s_load
  const float* __restrict__ c2b = c2 + s * NC;

  // staging ids: 2 threads per point, each loads 32 contiguous dims
  const int pl = tid >> 1;          // point-in-tile 0..255
  const int hh = tid & 1;           // dim half
  // compute ids: 1 point per thread, half the centroids
  const int p = tid & 255;          // point-in-tile
  const int h = tid >> 8;           // centroid half (0: k<128, 1: k>=128)

  const size_t xbase = (size_t)(chunk * PTS_PER_BLOCK) * (NS * DIM) + (size_t)s * DIM;

  float4 stage[8];
  {
    const float4* src = (const float4*)(x + xbase + (size_t)pl * (NS * DIM)) + hh * 8;
    #pragma unroll
    for (int j = 0; j < 8; ++j) stage[j] = src[j];
  }

  for (int t = 0; t < NTILES; ++t) {
    __syncthreads();   // xt free to overwrite (also covers ss init at t=0)
    #pragma unroll
    for (int j = 0; j < 8; ++j) {
      const float4 v = stage[j];
      const int d0 = hh * 32 + j * 4;
      xt[d0 + 0][pl] = v.x; xt[d0 + 1][pl] = v.y;
      xt[d0 + 2][pl] = v.z; xt[d0 + 3][pl] = v.w;
    }
    if (t + 1 < NTILES) {  // prefetch next tile into regs; latency hides under compute
      const float4* src =
          (const float4*)(x + xbase + (size_t)((t + 1) * TILE + pl) * (NS * DIM)) + hh * 8;
      #pragma unroll
      for (int j = 0; j < 8; ++j) stage[j] = src[j];
    }
    __syncthreads();   // xt ready

    float bestd = FLT_MAX;
    int bi = 0;
    const int kbase = h * HALF;
    #pragma unroll 2
    for (int k0 = kbase; k0 < kbase + HALF; k0 += 4) {
      float a0 = 0.f, a1 = 0.f, a2 = 0.f, a3 = 0.f;
      #pragma unroll
      for (int d = 0; d < DIM; ++d) {
        const float xd = xt[d][p];                    // ds_read_b32, imm offset d*1024
        a0 = fmaf(cb[(k0 + 0) * DIM + d], xd, a0);    // SGPR * VGPR + VGPR
        a1 = fmaf(cb[(k0 + 1) * DIM + d], xd, a1);
        a2 = fmaf(cb[(k0 + 2) * DIM + d], xd, a2);
        a3 = fmaf(cb[(k0 + 3) * DIM + d], xd, a3);
      }
      const float d0 = fmaf(-2.f, a0, c2b[k0 + 0]);
      const float d1 = fmaf(-2.f, a1, c2b[k0 + 1]);
      const float d2 = fmaf(-2.f, a2, c2b[k0 + 2]);
      const float d3 = fmaf(-2.f, a3, c2b[k0 + 3]);
      if (d0 < bestd) { bestd = d0; bi = k0 + 0; }
      if (d1 < bestd) { bestd = d1; bi = k0 + 1; }
      if (d2 < bestd) { bestd = d2; bi = k0 + 2; }
      if (d3 < bestd) { bestd = d3; bi = k0 + 3; }
    }

    if (h == 1) { sd[p] = bestd; si[p] = bi; }
    __syncthreads();
    if (h == 0) {
      const float od = sd[p];
      // strict <: h0 covers lower k, so ties go to h0 == first-min semantics
      if (od < bestd) { bestd = od; bi = si[p]; }
      atomicAdd(&scnt[bi], 1.0f);
      #pragma unroll
      for (int d = 0; d < DIM; ++d) atomicAdd(&ss[d * NC + bi], xt[d][p]);
    }
  }

  __syncthreads();
  float* __restrict__ sb = sums + (size_t)s * NC * DIM;
  for (int i = tid; i < DIM * NC; i += TPB) {
    const int d = i >> 8;
    const int k = i & 255;
    unsafeAtomicAdd(&sb[k * DIM + d], ss[i]);
  }
  if (tid < NC) unsafeAtomicAdd(&counts[s * NC + tid], scnt[tid]);
}

extern "C" void kernel_launch(void* const* d_in, const int* in_sizes, int n_in,
                              void* d_out, int out_size, void* d_ws, size_t ws_size,
                              hipStream_t stream) {
  const float* x = (const float*)d_in[0];
  float* c = (float*)d_out;                      // centroids live in d_out
  float* sums = (float*)d_ws;                    // [NS][NC][DIM]
  float* counts = sums + (size_t)NS * NC * DIM;  // [NS][NC]
  float* c2 = counts + NS * NC;                  // [NS][NC]

  kminit<<<NS * NC / 4, 256, 0, stream>>>(x, c, c2);
  for (int it = 0; it < NITER; ++it) {
    hipMemsetAsync(d_ws, 0, (size_t)(NS * NC * DIM + NS * NC) * sizeof(float), stream);
    kmassign<<<NS * CHUNKS, TPB, 0, stream>>>(x, c, c2, sums, counts);
    kmupdate<<<NS * NC / 4, 256, 0, stream>>>(c, sums, counts, c2);
  }
}

// Round 6
// 4559.765 us; speedup vs baseline: 1.4463x; 1.4463x over previous
//
#include <hip/hip_runtime.h>
#include <hip/hip_bf16.h>
#include <cfloat>

// K-means, 16 independent spaces. x: (32768, 16, 64) fp32. Output: (16, 256, 64) fp32.
#define NS 16
#define NPTS 32768
#define DIM 64
#define NC 256
#define NITER 5

constexpr int TPB = 512;
constexpr int CHUNKS = 16;                       // 256 blocks = 1/CU
constexpr int PTS_PER_BLOCK = NPTS / CHUNKS;     // 2048
constexpr int TILE = 256;                        // points staged in LDS at once
constexpr int NTILES = PTS_PER_BLOCK / TILE;     // 8

// c0[s][k][d] = x[k][s][d]; ct[s][d][k] transposed copy; c2[s][k] = sum_d c^2
__global__ __launch_bounds__(256) void kminit(const float* __restrict__ x,
                                              float* __restrict__ c,
                                              float* __restrict__ ct,
                                              float* __restrict__ c2) {
  const int tid = threadIdx.x;
  const int g = blockIdx.x * 4 + (tid >> 6);
  const int lane = tid & 63;
  const int s = g >> 8;
  const int k = g & 255;
  float v = x[(size_t)k * (NS * DIM) + s * DIM + lane];
  c[(size_t)g * DIM + lane] = v;
  ct[((size_t)s * DIM + lane) * NC + k] = v;
  float sq = v * v;
  #pragma unroll
  for (int off = 32; off; off >>= 1) sq += __shfl_xor(sq, off);
  if (lane == 0) c2[g] = sq;
}

// c = counts>0 ? sums/max(counts,1) : c ; refresh ct, c2
__global__ __launch_bounds__(256) void kmupdate(float* __restrict__ c,
                                                const float* __restrict__ sums,
                                                const float* __restrict__ counts,
                                                float* __restrict__ ct,
                                                float* __restrict__ c2) {
  const int tid = threadIdx.x;
  const int g = blockIdx.x * 4 + (tid >> 6);
  const int lane = tid & 63;
  const int s = g >> 8;
  const int k = g & 255;
  const float cnt = counts[g];
  const size_t idx = (size_t)g * DIM + lane;
  const float cold = c[idx];
  const float v = (cnt > 0.f) ? (sums[idx] / fmaxf(cnt, 1.f)) : cold;
  c[idx] = v;
  ct[((size_t)s * DIM + lane) * NC + k] = v;
  float sq = v * v;
  #pragma unroll
  for (int off = 32; off; off >>= 1) sq += __shfl_xor(sq, off);
  if (lane == 0) c2[g] = sq;
}

// Fused assign + accumulate, register-blocked (R5 post-mortem):
//  R5 was LDS-issue-bound: 1 ds_read_b32 per 4 FMAs (3x oversubscribed).
//  Now: thread = 2 points x 32 centroids per d-step = 1 ds_read_b64 per 64
//  FMAs (8 waves x 6 cyc = 48 LDS cyc per 128 VALU cyc -> VALU-bound).
//  512 thr = 128 pt-pairs x 4 wave-uniform k-groups (readfirstlane -> SGPR).
//  Centroids read from transposed ct[s][d][k] -> 32 contiguous floats per
//  (d, k-block) -> s_load_dwordx16 on the scalar pipe (proven path, R1).
//  acc[2][32] is RMW accumulator state (regalloc keeps in VGPRs), unlike
//  R1/R4's load-once xv[64] which spilled.
__global__ __launch_bounds__(TPB)
__attribute__((amdgpu_waves_per_eu(2, 2)))
void kmassign(const float* __restrict__ x,
              const float* __restrict__ ct,
              const float* __restrict__ c2,
              float* __restrict__ sums,
              float* __restrict__ counts) {
  __shared__ float xt[DIM][TILE];   // 64 KiB transposed point tile
  __shared__ float ss[DIM * NC];    // 64 KiB partial sums [d][k]
  __shared__ float sd[4][TILE];     // per-group best dist
  __shared__ int   si[4][TILE];     // per-group best idx
  __shared__ float scnt[NC];        // per-block counts

  const int tid = threadIdx.x;
  const int s = blockIdx.x & (NS - 1);
  const int chunk = blockIdx.x >> 4;

  for (int i = tid; i < DIM * NC; i += TPB) ss[i] = 0.f;
  if (tid < NC) scnt[tid] = 0.f;

  // staging ids: 2 threads per point, each loads 32 contiguous dims
  const int pl = tid >> 1;
  const int hh = tid & 1;
  // compute ids: pair of points x wave-uniform centroid quarter
  const int pp = tid & 127;                                   // point pair 0..127
  const int kgroup = __builtin_amdgcn_readfirstlane(tid) >> 7; // 0..3, SGPR

  const float* __restrict__ c2b = c2 + s * NC;                 // block-uniform
  const float* __restrict__ ctb = ct + (size_t)s * (DIM * NC); // block-uniform

  const size_t xbase = (size_t)(chunk * PTS_PER_BLOCK) * (NS * DIM) + (size_t)s * DIM;

  float4 stage[8];
  {
    const float4* src = (const float4*)(x + xbase + (size_t)pl * (NS * DIM)) + hh * 8;
    #pragma unroll
    for (int j = 0; j < 8; ++j) stage[j] = src[j];
  }

  for (int t = 0; t < NTILES; ++t) {
    __syncthreads();   // xt free to overwrite (prev scatter done; ss init at t=0)
    #pragma unroll
    for (int j = 0; j < 8; ++j) {
      const float4 v = stage[j];
      const int d0 = hh * 32 + j * 4;
      xt[d0 + 0][pl] = v.x; xt[d0 + 1][pl] = v.y;
      xt[d0 + 2][pl] = v.z; xt[d0 + 3][pl] = v.w;
    }
    __syncthreads();   // xt ready

    float bd0 = FLT_MAX, bd1 = FLT_MAX;
    int bi0 = 0, bi1 = 0;
    #pragma unroll
    for (int kb = 0; kb < 2; ++kb) {
      const float* __restrict__ ctg = ctb + kgroup * 64 + kb * 32;  // uniform
      float acc0[32], acc1[32];
      #pragma unroll
      for (int j = 0; j < 32; ++j) { acc0[j] = 0.f; acc1[j] = 0.f; }
      #pragma unroll 8
      for (int d = 0; d < DIM; ++d) {
        const float2 xp = *(const float2*)&xt[d][2 * pp];   // ds_read_b64
        #pragma unroll
        for (int j = 0; j < 32; ++j) {
          const float cv = ctg[(size_t)d * NC + j];          // s_load (uniform)
          acc0[j] = fmaf(cv, xp.x, acc0[j]);
          acc1[j] = fmaf(cv, xp.y, acc1[j]);
        }
      }
      #pragma unroll
      for (int j = 0; j < 32; ++j) {
        const int k = kgroup * 64 + kb * 32 + j;
        const float c2v = c2b[k];
        const float d0 = fmaf(-2.f, acc0[j], c2v);
        const float d1 = fmaf(-2.f, acc1[j], c2v);
        // ascending k + strict < == jnp.argmin first-min tie-break
        if (d0 < bd0) { bd0 = d0; bi0 = k; }
        if (d1 < bd1) { bd1 = d1; bi1 = k; }
      }
    }

    if (t + 1 < NTILES) {  // prefetch next tile; covered by merge+scatter phases
      const float4* src =
          (const float4*)(x + xbase + (size_t)((t + 1) * TILE + pl) * (NS * DIM)) + hh * 8;
      #pragma unroll
      for (int j = 0; j < 8; ++j) stage[j] = src[j];
    }

    sd[kgroup][2 * pp] = bd0;     si[kgroup][2 * pp] = bi0;
    sd[kgroup][2 * pp + 1] = bd1; si[kgroup][2 * pp + 1] = bi1;
    __syncthreads();

    if (tid < TILE) {  // 4-way merge, group order == k order -> first-min ties
      const int p = tid;
      float bd = sd[0][p];
      int bi = si[0][p];
      #pragma unroll
      for (int g = 1; g < 4; ++g) {
        const float od = sd[g][p];
        if (od < bd) { bd = od; bi = si[g][p]; }
      }
      si[0][p] = bi;
    }
    __syncthreads();

    {  // scatter: all 512 threads, each does 32 dims of one point
      const int p = tid >> 1;
      const int dh = tid & 1;
      const int bi = si[0][p];
      if (dh == 0) atomicAdd(&scnt[bi], 1.0f);
      #pragma unroll
      for (int d = dh * 32; d < dh * 32 + 32; ++d)
        atomicAdd(&ss[d * NC + bi], xt[d][p]);
    }
  }

  __syncthreads();
  float* __restrict__ sb = sums + (size_t)s * NC * DIM;
  for (int i = tid; i < DIM * NC; i += TPB) {
    const int d = i >> 8;
    const int k = i & 255;
    unsafeAtomicAdd(&sb[k * DIM + d], ss[i]);
  }
  if (tid < NC) unsafeAtomicAdd(&counts[s * NC + tid], scnt[tid]);
}

extern "C" void kernel_launch(void* const* d_in, const int* in_sizes, int n_in,
                              void* d_out, int out_size, void* d_ws, size_t ws_size,
                              hipStream_t stream) {
  const float* x = (const float*)d_in[0];
  float* c = (float*)d_out;                      // centroids live in d_out
  float* sums = (float*)d_ws;                    // [NS][NC][DIM]  1 MiB
  float* counts = sums + (size_t)NS * NC * DIM;  // [NS][NC]
  float* c2 = counts + NS * NC;                  // [NS][NC]
  float* ct = c2 + NS * NC;                      // [NS][DIM][NC]  1 MiB

  kminit<<<NS * NC / 4, 256, 0, stream>>>(x, c, ct, c2);
  for (int it = 0; it < NITER; ++it) {
    hipMemsetAsync(d_ws, 0, (size_t)(NS * NC * DIM + NS * NC) * sizeof(float), stream);
    kmassign<<<NS * CHUNKS, TPB, 0, stream>>>(x, ct, c2, sums, counts);
    kmupdate<<<NS * NC / 4, 256, 0, stream>>>(c, sums, counts, ct, c2);
  }
}

// Round 10
// 1600.021 us; speedup vs baseline: 4.1216x; 2.8498x over previous
//
#include <hip/hip_runtime.h>
#include <hip/hip_bf16.h>
#include <cfloat>

// K-means, 16 spaces. x: (32768, 16, 64) fp32. Output: (16, 256, 64) fp32.
#define NS 16
#define NPTS 32768
#define DIM 64
#define NC 256
#define NITER 5

constexpr int TPB = 512;                      // 8 waves
constexpr int CHUNKS = 32;                    // 512 blocks
constexpr int PTS_PER_BLOCK = NPTS / CHUNKS;  // 1024
constexpr int PSUM_STRIDE = NC * DIM + NC;    // 16640 floats per block partial

typedef __attribute__((ext_vector_type(8))) short bf16x8;
typedef __attribute__((ext_vector_type(4))) float f32x4;

__device__ __forceinline__ unsigned f2bf(float f) {   // fp32 -> bf16 bits, RNE
  unsigned u = __float_as_uint(f);
  u += 0x7FFFu + ((u >> 16) & 1u);
  return u >> 16;
}
__device__ __forceinline__ float bf2f(unsigned h) { return __uint_as_float(h << 16); }

// 3-piece split: v = h + m + l, relative error 2^-27 (bf16 exponent range ==
// fp32, so no subnormal hazard). R7's 2-piece split (2^-18) caused ~1.2e-4
// distance error -> argmin flips -> absmax 0.25. 3 pieces -> ~1e-6 (= fp32 ref).
__device__ __forceinline__ void split3(float v, unsigned short& h,
                                       unsigned short& m, unsigned short& l) {
  const unsigned hh = f2bf(v);
  const float r1 = v - bf2f(hh);
  const unsigned mm = f2bf(r1);
  const float r2 = r1 - bf2f(mm);
  h = (unsigned short)hh; m = (unsigned short)mm; l = (unsigned short)f2bf(r2);
}

// c0[s][k][d] = x[k][s][d]; emit fp32 c (d_out), 3-piece bf16 split, c2.
__global__ __launch_bounds__(256) void kminit(const float* __restrict__ x,
                                              float* __restrict__ c,
                                              unsigned short* __restrict__ c_h,
                                              unsigned short* __restrict__ c_m,
                                              unsigned short* __restrict__ c_l,
                                              float* __restrict__ c2) {
  const int tid = threadIdx.x;
  const int g = blockIdx.x * 4 + (tid >> 6);
  const int lane = tid & 63;
  const int s = g >> 8, k = g & 255;
  const float v = x[(size_t)k * (NS * DIM) + s * DIM + lane];
  const size_t idx = (size_t)g * DIM + lane;
  c[idx] = v;
  split3(v, c_h[idx], c_m[idx], c_l[idx]);
  float sq = v * v;
  #pragma unroll
  for (int off = 32; off; off >>= 1) sq += __shfl_xor(sq, off);
  if (lane == 0) c2[g] = sq;
}

// c = counts>0 ? sums/max(counts,1) : c ; refresh split + c2.
__global__ __launch_bounds__(256) void kmupdate(float* __restrict__ c,
                                                unsigned short* __restrict__ c_h,
                                                unsigned short* __restrict__ c_m,
                                                unsigned short* __restrict__ c_l,
                                                float* __restrict__ c2,
                                                const float* __restrict__ sums,
                                                const float* __restrict__ counts,
                                                const float* __restrict__ psum,
                                                const int usePsum) {
  const int tid = threadIdx.x;
  const int g = blockIdx.x * 4 + (tid >> 6);
  const int lane = tid & 63;
  const int s = g >> 8, k = g & 255;
  float sv, cnt;
  if (usePsum) {
    sv = 0.f; cnt = 0.f;
    for (int ch = 0; ch < CHUNKS; ++ch) {          // kmassign bx = ch*16 + s
      const float* __restrict__ pb = psum + (size_t)(ch * NS + s) * PSUM_STRIDE;
      sv += pb[k * DIM + lane];
      cnt += pb[NC * DIM + k];
    }
  } else {
    sv = sums[(size_t)g * DIM + lane];
    cnt = counts[g];
  }
  const size_t idx = (size_t)g * DIM + lane;
  const float cold = c[idx];
  const float v = (cnt > 0.f) ? (sv / fmaxf(cnt, 1.f)) : cold;
  c[idx] = v;
  split3(v, c_h[idx], c_m[idx], c_l[idx]);
  float sq = v * v;
  #pragma unroll
  for (int off = 32; off; off >>= 1) sq += __shfl_xor(sq, off);
  if (lane == 0) c2[g] = sq;
}

// MFMA assign + fused argmin + scatter. dist = c2[k] - 2*dot (x^2 dropped,
// argmin-invariant). dot via 3-piece split, 6 terms: hh,hm,mh,hl,lh,mm.
// Layout (validated by R7's error magnitude): A/B symmetric k-slot wiring;
// D: col=lane&15 (point), row=4*(lane>>4)+reg (centroid) [HW-verified m89].
// Each wave: 2 half-passes x 2 col-tiles x 16 points. Two independent 6-deep
// acc chains per ct (4 chains/wave) for MFMA pipelining.
__global__ __launch_bounds__(TPB)
__attribute__((amdgpu_waves_per_eu(2, 2)))
void kmassign(const float* __restrict__ x,
              const unsigned short* __restrict__ c_h,
              const unsigned short* __restrict__ c_m,
              const unsigned short* __restrict__ c_l,
              const float* __restrict__ c2,
              float* __restrict__ sums, float* __restrict__ counts,
              float* __restrict__ psum, const int usePsum) {
  __shared__ float ss[DIM * 257];   // 65792 B, padded: bank(d,k)=(d+k)%32
  __shared__ float scnt[NC];

  const int tid = threadIdx.x;
  const int bx = blockIdx.x;
  const int s = bx & (NS - 1);
  const int chunk = bx >> 4;

  for (int i = tid; i < DIM * 257; i += TPB) ss[i] = 0.f;
  if (tid < NC) scnt[tid] = 0.f;
  __syncthreads();

  const int lane = tid & 63;
  const int wid = tid >> 6;        // 0..7
  const int lrow = lane & 15;
  const int g = lane >> 4;         // 0..3

  const unsigned short* __restrict__ chb = c_h + (size_t)s * (NC * DIM);
  const unsigned short* __restrict__ cmb = c_m + (size_t)s * (NC * DIM);
  const unsigned short* __restrict__ clb = c_l + (size_t)s * (NC * DIM);
  const float* __restrict__ c2b = c2 + s * NC;

  for (int grp = 0; grp < 2; ++grp) {
    for (int half = 0; half < 2; ++half) {
      // ---- build B pieces: 2 col-tiles x 16 points x (2 k-chunks) ----
      bf16x8 BH[2][2], BM[2][2], BL[2][2];
      #pragma unroll
      for (int ct = 0; ct < 2; ++ct) {
        const int p = chunk * PTS_PER_BLOCK + grp * 512 + wid * 64 +
                      half * 32 + ct * 16 + lrow;
        const float* __restrict__ xp = x + (size_t)p * (NS * DIM) + s * DIM;
        #pragma unroll
        for (int cc = 0; cc < 2; ++cc) {   // k-chunk: dims cc*32 + 8g .. +7
          const float4 a0 = *(const float4*)(xp + cc * 32 + 8 * g);
          const float4 a1 = *(const float4*)(xp + cc * 32 + 8 * g + 4);
          const float vv[8] = {a0.x, a0.y, a0.z, a0.w, a1.x, a1.y, a1.z, a1.w};
          #pragma unroll
          for (int j = 0; j < 8; ++j) {
            unsigned short h, m, l;
            split3(vv[j], h, m, l);
            BH[ct][cc][j] = (short)h; BM[ct][cc][j] = (short)m; BL[ct][cc][j] = (short)l;
          }
        }
      }

      float bd[2] = {FLT_MAX, FLT_MAX};
      int bk[2] = {0, 0};

      #pragma unroll 2
      for (int kt = 0; kt < 16; ++kt) {
        const size_t ko = (size_t)(kt * 16 + lrow) * DIM + 8 * g;
        const bf16x8 ah0 = *(const bf16x8*)(chb + ko);
        const bf16x8 ah1 = *(const bf16x8*)(chb + ko + 32);
        const bf16x8 am0 = *(const bf16x8*)(cmb + ko);
        const bf16x8 am1 = *(const bf16x8*)(cmb + ko + 32);
        const bf16x8 al0 = *(const bf16x8*)(clb + ko);
        const bf16x8 al1 = *(const bf16x8*)(clb + ko + 32);
        const float4 c2v = *(const float4*)(c2b + kt * 16 + 4 * g);
        const float cva[4] = {c2v.x, c2v.y, c2v.z, c2v.w};
        #pragma unroll
        for (int ct = 0; ct < 2; ++ct) {
          f32x4 accA = {0.f, 0.f, 0.f, 0.f};   // hh + mh + lh
          f32x4 accB = {0.f, 0.f, 0.f, 0.f};   // hm + hl + mm
          accA = __builtin_amdgcn_mfma_f32_16x16x32_bf16(ah0, BH[ct][0], accA, 0, 0, 0);
          accB = __builtin_amdgcn_mfma_f32_16x16x32_bf16(ah0, BM[ct][0], accB, 0, 0, 0);
          accA = __builtin_amdgcn_mfma_f32_16x16x32_bf16(ah1, BH[ct][1], accA, 0, 0, 0);
          accB = __builtin_amdgcn_mfma_f32_16x16x32_bf16(ah1, BM[ct][1], accB, 0, 0, 0);
          accA = __builtin_amdgcn_mfma_f32_16x16x32_bf16(am0, BH[ct][0], accA, 0, 0, 0);
          accB = __builtin_amdgcn_mfma_f32_16x16x32_bf16(ah0, BL[ct][0], accB, 0, 0, 0);
          accA = __builtin_amdgcn_mfma_f32_16x16x32_bf16(am1, BH[ct][1], accA, 0, 0, 0);
          accB = __builtin_amdgcn_mfma_f32_16x16x32_bf16(ah1, BL[ct][1], accB, 0, 0, 0);
          accA = __builtin_amdgcn_mfma_f32_16x16x32_bf16(al0, BH[ct][0], accA, 0, 0, 0);
          accB = __builtin_amdgcn_mfma_f32_16x16x32_bf16(am0, BM[ct][0], accB, 0, 0, 0);
          accA = __builtin_amdgcn_mfma_f32_16x16x32_bf16(al1, BH[ct][1], accA, 0, 0, 0);
          accB = __builtin_amdgcn_mfma_f32_16x16x32_bf16(am1, BM[ct][1], accB, 0, 0, 0);
          #pragma unroll
          for (int r = 0; r < 4; ++r) {
            const int k = kt * 16 + 4 * g + r;     // D row = 4g + r
            const float dd = fmaf(-2.f, accA[r] + accB[r], cva[r]);
            if (dd < bd[ct] || (dd == bd[ct] && k < bk[ct])) { bd[ct] = dd; bk[ct] = k; }
          }
        }
      }

      // ---- cross-lane argmin over 4 row-groups, count, scatter ----
      #pragma unroll
      for (int ct = 0; ct < 2; ++ct) {
        float b = bd[ct]; int kk = bk[ct];
        #pragma unroll
        for (int off = 16; off <= 32; off <<= 1) {
          const float od = __shfl_xor(b, off);
          const int ok = __shfl_xor(kk, off);
          if (od < b || (od == b && ok < kk)) { b = od; kk = ok; }
        }
        if (g == 0) atomicAdd(&scnt[kk], 1.f);
        #pragma unroll
        for (int j = 0; j < 8; ++j) {   // x reconstructed = h+m+l (2^-27)
          const float v0 = bf2f((unsigned short)BH[ct][0][j]) +
                           bf2f((unsigned short)BM[ct][0][j]) +
                           bf2f((unsigned short)BL[ct][0][j]);
          const float v1 = bf2f((unsigned short)BH[ct][1][j]) +
                           bf2f((unsigned short)BM[ct][1][j]) +
                           bf2f((unsigned short)BL[ct][1][j]);
          atomicAdd(&ss[(8 * g + j) * 257 + kk], v0);
          atomicAdd(&ss[(32 + 8 * g + j) * 257 + kk], v1);
        }
      }
    }
  }

  __syncthreads();
  if (usePsum) {   // plain coalesced partial store; no global atomics, no memset
    float* __restrict__ pb = psum + (size_t)bx * PSUM_STRIDE;
    for (int i = tid; i < DIM * NC; i += TPB) {
      const int k = i >> 6, d = i & 63;
      pb[i] = ss[d * 257 + k];                 // pb[k*64+d]
    }
    if (tid < NC) pb[NC * DIM + tid] = scnt[tid];
  } else {
    float* __restrict__ sb = sums + (size_t)s * (NC * DIM);
    for (int i = tid; i < DIM * NC; i += TPB) {
      const int k = i >> 6, d = i & 63;
      unsafeAtomicAdd(&sb[i], ss[d * 257 + k]);
    }
    if (tid < NC) unsafeAtomicAdd(&counts[s * NC + tid], scnt[tid]);
  }
}

extern "C" void kernel_launch(void* const* d_in, const int* in_sizes, int n_in,
                              void* d_out, int out_size, void* d_ws, size_t ws_size,
                              hipStream_t stream) {
  const float* x = (const float*)d_in[0];
  float* c = (float*)d_out;
  float* ws = (float*)d_ws;
  // ws layout (float slots):
  float* sums = ws;                                        // 262144
  float* counts = ws + 262144;                             // 4096
  float* c2 = ws + 266240;                                 // 4096
  unsigned short* c_h = (unsigned short*)(ws + 270336);    // 131072 fslots
  unsigned short* c_m = (unsigned short*)(ws + 401408);    // 131072 fslots
  unsigned short* c_l = (unsigned short*)(ws + 532480);    // 131072 fslots
  float* psum = ws + 663552;                               // 512 * 16640
  const size_t need = ((size_t)663552 + (size_t)NS * CHUNKS * PSUM_STRIDE) * 4;
  const int usePsum = (ws_size >= need) ? 1 : 0;

  kminit<<<NS * NC / 4, 256, 0, stream>>>(x, c, c_h, c_m, c_l, c2);
  for (int it = 0; it < NITER; ++it) {
    if (!usePsum)
      hipMemsetAsync(sums, 0, (size_t)(NC * DIM * NS + NS * NC) * sizeof(float), stream);
    kmassign<<<NS * CHUNKS, TPB, 0, stream>>>(x, c_h, c_m, c_l, c2,
                                              sums, counts, psum, usePsum);
    kmupdate<<<NS * NC / 4, 256, 0, stream>>>(c, c_h, c_m, c_l, c2,
                                              sums, counts, psum, usePsum);
  }
}